// Round 1
// baseline (1261.661 us; speedup 1.0000x reference)
//
#include <hip/hip_runtime.h>
#include <hip/hip_bf16.h>
#include <cstdint>
#include <cstddef>

// Problem constants
#define B_   16
#define S_   4096
#define D_   64
#define TQ   64      // Q rows per block (4 waves x 16)
#define TK   64      // keys per LDS tile
#define KSTR 72      // LDS row stride (ushorts) for K tile: 64 + 8 pad -> 144 B
#define VSTR 72
#define PSTR 72
#define CTX_ELEMS (B_*S_*D_)   // 4194304 floats; attn follows in d_out

typedef __attribute__((ext_vector_type(8))) short short8;  // 8 bf16 = 4 VGPRs
typedef __attribute__((ext_vector_type(4))) float f32x4;

static __device__ __forceinline__ unsigned short f2bf(float f) {
  union { float f; unsigned int u; } v; v.f = f;
  unsigned int r = (v.u + 0x7FFFu + ((v.u >> 16) & 1u)) >> 16;  // RN-even
  return (unsigned short)r;
}

// ---- pre-pass 1: elementwise fp32 -> bf16 (for K) ----
__global__ __launch_bounds__(256) void conv_bf16_kernel(
    const float* __restrict__ src, unsigned short* __restrict__ dst) {
  int i = blockIdx.x * 256 + threadIdx.x;        // handles 8 elems
  const float4* s = (const float4*)src;
  float4 a = s[(size_t)i*2], b = s[(size_t)i*2 + 1];
  unsigned int u0 = (unsigned)f2bf(a.x) | ((unsigned)f2bf(a.y) << 16);
  unsigned int u1 = (unsigned)f2bf(a.z) | ((unsigned)f2bf(a.w) << 16);
  unsigned int u2 = (unsigned)f2bf(b.x) | ((unsigned)f2bf(b.y) << 16);
  unsigned int u3 = (unsigned)f2bf(b.z) | ((unsigned)f2bf(b.w) << 16);
  uint4 o; o.x = u0; o.y = u1; o.z = u2; o.w = u3;
  *(uint4*)(dst + (size_t)i * 8) = o;
}

// ---- pre-pass 2: V [b][k][d] fp32 -> Vt [b][d][k] bf16 (LDS transpose) ----
__global__ __launch_bounds__(256) void convVt_kernel(
    const float* __restrict__ V, unsigned short* __restrict__ Vt) {
  __shared__ unsigned short lsT[D_ * VSTR];
  const int tid = threadIdx.x;
  const int b = blockIdx.y, k0 = blockIdx.x * 64;
  const float4* src = (const float4*)(V + ((size_t)(b * S_ + k0)) * D_);
#pragma unroll
  for (int i = 0; i < 4; ++i) {
    int li = tid + 256 * i;           // 1024 float4 = 64 keys x 16
    int row = li >> 4, c4 = li & 15;  // row = key, c4 = dim group
    float4 v = src[row * 16 + c4];
    lsT[(c4 * 4 + 0) * VSTR + row] = f2bf(v.x);
    lsT[(c4 * 4 + 1) * VSTR + row] = f2bf(v.y);
    lsT[(c4 * 4 + 2) * VSTR + row] = f2bf(v.z);
    lsT[(c4 * 4 + 3) * VSTR + row] = f2bf(v.w);
  }
  __syncthreads();
#pragma unroll
  for (int i = 0; i < 2; ++i) {
    int li = tid + 256 * i;           // 512 x 16B = 64 d-rows x 128 B
    int d = li >> 3, c = li & 7;
    uint4 v = *(const uint4*)&lsT[d * VSTR + c * 8];
    *(uint4*)(Vt + ((size_t)(b * D_ + d)) * S_ + k0 + c * 8) = v;
  }
}

// ---- main fused attention kernel ----
// Sweep 1: l = sum_k exp2(score*log2e + bias)   (recompute-based softmax denom)
// Sweep 2: p = exp2(.)/l -> store attn fp32; P->LDS bf16 -> PV MFMA -> context
template<bool PRE>
__global__ __launch_bounds__(256, 2) void attn_kernel(
    const float* __restrict__ Q,
    const unsigned short* __restrict__ K16,
    const unsigned short* __restrict__ Vt16,
    const float* __restrict__ K32,
    const float* __restrict__ V32,
    const int* __restrict__ mask,
    float* __restrict__ out) {
  __shared__ unsigned short lsK[TK * KSTR];       // 9216 B
  __shared__ unsigned short lsV[D_ * VSTR];       // 9216 B (V transposed: [d][k])
  __shared__ unsigned short lsP[4 * 16 * PSTR];   // 9216 B (per-wave P tiles)
  __shared__ float lsBias[S_];                    // 16384 B

  const int tid = threadIdx.x;
  const int wave = tid >> 6, lane = tid & 63;
  const int quad = lane >> 4, n = lane & 15;

  // swizzle: 2 batches per XCD (g%8 = XCD round-robin heuristic, perf-only)
  const int g = blockIdx.x;
  const int b = (g & 7) * 2 + ((g >> 3) & 1);
  const int qt = g >> 4;
  const int qbase = qt * TQ;
  const int bS = b * S_;

  // mask -> additive bias for the whole row of keys (once per block)
  for (int i = tid; i < S_; i += 256)
    lsBias[i] = mask[bS + i] ? -1e30f : 0.0f;

  // Q A-fragments: lane m = lane&15, k = quad*8+j ; fold scale*log2e into Q
  const float QSC = 0.125f * 1.44269504088896340736f;
  const int qrowA = qbase + wave * 16 + n;
  const float* qp = Q + ((size_t)(bS + qrowA)) * D_ + quad * 8;
  short8 aq0, aq1;
  {
    float4 f0 = *(const float4*)(qp);
    float4 f1 = *(const float4*)(qp + 4);
    float4 f2 = *(const float4*)(qp + 32);
    float4 f3 = *(const float4*)(qp + 36);
    aq0[0] = (short)f2bf(f0.x * QSC); aq0[1] = (short)f2bf(f0.y * QSC);
    aq0[2] = (short)f2bf(f0.z * QSC); aq0[3] = (short)f2bf(f0.w * QSC);
    aq0[4] = (short)f2bf(f1.x * QSC); aq0[5] = (short)f2bf(f1.y * QSC);
    aq0[6] = (short)f2bf(f1.z * QSC); aq0[7] = (short)f2bf(f1.w * QSC);
    aq1[0] = (short)f2bf(f2.x * QSC); aq1[1] = (short)f2bf(f2.y * QSC);
    aq1[2] = (short)f2bf(f2.z * QSC); aq1[3] = (short)f2bf(f2.w * QSC);
    aq1[4] = (short)f2bf(f3.x * QSC); aq1[5] = (short)f2bf(f3.y * QSC);
    aq1[6] = (short)f2bf(f3.z * QSC); aq1[7] = (short)f2bf(f3.w * QSC);
  }

  // ---------------- sweep 1: denominators ----------------
  float l0 = 0.f, l1 = 0.f, l2 = 0.f, l3 = 0.f;
  for (int kt = 0; kt < S_ / TK; ++kt) {
    const int k0 = kt * TK;
    __syncthreads();
    if (PRE) {
#pragma unroll
      for (int i = 0; i < 2; ++i) {
        int li = tid + 256 * i;
        int row = li >> 3, c = li & 7;
        uint4 v = *(const uint4*)(K16 + ((size_t)(bS + k0 + row)) * D_ + c * 8);
        *(uint4*)&lsK[row * KSTR + c * 8] = v;
      }
    } else {
#pragma unroll
      for (int i = 0; i < 4; ++i) {
        int li = tid + 256 * i;
        int row = li >> 4, c4 = li & 15;
        float4 v = *(const float4*)(K32 + ((size_t)(bS + k0 + row)) * D_ + c4 * 4);
        unsigned int u0 = (unsigned)f2bf(v.x) | ((unsigned)f2bf(v.y) << 16);
        unsigned int u1 = (unsigned)f2bf(v.z) | ((unsigned)f2bf(v.w) << 16);
        uint2 uu; uu.x = u0; uu.y = u1;
        *(uint2*)&lsK[row * KSTR + c4 * 4] = uu;
      }
    }
    __syncthreads();
#pragma unroll
    for (int ch = 0; ch < 4; ++ch) {
      short8 kb0 = *(const short8*)&lsK[(ch * 16 + n) * KSTR + quad * 8];
      short8 kb1 = *(const short8*)&lsK[(ch * 16 + n) * KSTR + 32 + quad * 8];
      f32x4 c = {0.f, 0.f, 0.f, 0.f};
      c = __builtin_amdgcn_mfma_f32_16x16x32_bf16(aq0, kb0, c, 0, 0, 0);
      c = __builtin_amdgcn_mfma_f32_16x16x32_bf16(aq1, kb1, c, 0, 0, 0);
      float bias = lsBias[k0 + ch * 16 + n];
      l0 += exp2f(c[0] + bias);
      l1 += exp2f(c[1] + bias);
      l2 += exp2f(c[2] + bias);
      l3 += exp2f(c[3] + bias);
    }
  }
  // reduce across the 16 lanes of each quad (cols of each C-row live there)
  float rl[4];
  {
    float t[4] = {l0, l1, l2, l3};
#pragma unroll
    for (int r = 0; r < 4; ++r) {
      float x = t[r];
      x += __shfl_xor(x, 1); x += __shfl_xor(x, 2);
      x += __shfl_xor(x, 4); x += __shfl_xor(x, 8);
      rl[r] = 1.0f / x;
    }
  }

  // ---------------- sweep 2: attn write + PV ----------------
  f32x4 oc0 = {0.f,0.f,0.f,0.f}, oc1 = {0.f,0.f,0.f,0.f};
  f32x4 oc2 = {0.f,0.f,0.f,0.f}, oc3 = {0.f,0.f,0.f,0.f};
  float* attn = out + CTX_ELEMS;
  for (int kt = 0; kt < S_ / TK; ++kt) {
    const int k0 = kt * TK;
    __syncthreads();
    if (PRE) {
#pragma unroll
      for (int i = 0; i < 2; ++i) {
        int li = tid + 256 * i;
        int row = li >> 3, c = li & 7;
        uint4 v = *(const uint4*)(K16 + ((size_t)(bS + k0 + row)) * D_ + c * 8);
        *(uint4*)&lsK[row * KSTR + c * 8] = v;
      }
#pragma unroll
      for (int i = 0; i < 2; ++i) {
        int li = tid + 256 * i;
        int d = li >> 3, c = li & 7;
        uint4 v = *(const uint4*)(Vt16 + ((size_t)(b * D_ + d)) * S_ + k0 + c * 8);
        *(uint4*)&lsV[d * VSTR + c * 8] = v;
      }
    } else {
#pragma unroll
      for (int i = 0; i < 4; ++i) {
        int li = tid + 256 * i;
        int row = li >> 4, c4 = li & 15;
        float4 v = *(const float4*)(K32 + ((size_t)(bS + k0 + row)) * D_ + c4 * 4);
        unsigned int u0 = (unsigned)f2bf(v.x) | ((unsigned)f2bf(v.y) << 16);
        unsigned int u1 = (unsigned)f2bf(v.z) | ((unsigned)f2bf(v.w) << 16);
        uint2 uu; uu.x = u0; uu.y = u1;
        *(uint2*)&lsK[row * KSTR + c4 * 4] = uu;
        float4 vv = *(const float4*)(V32 + ((size_t)(bS + k0 + row)) * D_ + c4 * 4);
        lsV[(c4 * 4 + 0) * VSTR + row] = f2bf(vv.x);
        lsV[(c4 * 4 + 1) * VSTR + row] = f2bf(vv.y);
        lsV[(c4 * 4 + 2) * VSTR + row] = f2bf(vv.z);
        lsV[(c4 * 4 + 3) * VSTR + row] = f2bf(vv.w);
      }
    }
    __syncthreads();
#pragma unroll
    for (int ch = 0; ch < 4; ++ch) {
      short8 kb0 = *(const short8*)&lsK[(ch * 16 + n) * KSTR + quad * 8];
      short8 kb1 = *(const short8*)&lsK[(ch * 16 + n) * KSTR + 32 + quad * 8];
      f32x4 c = {0.f, 0.f, 0.f, 0.f};
      c = __builtin_amdgcn_mfma_f32_16x16x32_bf16(aq0, kb0, c, 0, 0, 0);
      c = __builtin_amdgcn_mfma_f32_16x16x32_bf16(aq1, kb1, c, 0, 0, 0);
      float bias = lsBias[k0 + ch * 16 + n];
#pragma unroll
      for (int r = 0; r < 4; ++r) {
        float p = exp2f(c[r] + bias) * rl[r];
        int qr = qbase + wave * 16 + quad * 4 + r;       // C-layout row
        __builtin_nontemporal_store(
            p, attn + ((size_t)(bS + qr)) * S_ + k0 + ch * 16 + n);
        lsP[(wave * 16 + quad * 4 + r) * PSTR + ch * 16 + n] = f2bf(p);
      }
    }
    // PV: A = P (LDS round-trip C->A layout), B = Vt rows (contiguous k)
#pragma unroll
    for (int ks = 0; ks < 2; ++ks) {
      short8 ap = *(const short8*)&lsP[(wave * 16 + n) * PSTR + ks * 32 + quad * 8];
      short8 bv0 = *(const short8*)&lsV[(0 * 16 + n) * VSTR + ks * 32 + quad * 8];
      short8 bv1 = *(const short8*)&lsV[(1 * 16 + n) * VSTR + ks * 32 + quad * 8];
      short8 bv2 = *(const short8*)&lsV[(2 * 16 + n) * VSTR + ks * 32 + quad * 8];
      short8 bv3 = *(const short8*)&lsV[(3 * 16 + n) * VSTR + ks * 32 + quad * 8];
      oc0 = __builtin_amdgcn_mfma_f32_16x16x32_bf16(ap, bv0, oc0, 0, 0, 0);
      oc1 = __builtin_amdgcn_mfma_f32_16x16x32_bf16(ap, bv1, oc1, 0, 0, 0);
      oc2 = __builtin_amdgcn_mfma_f32_16x16x32_bf16(ap, bv2, oc2, 0, 0, 0);
      oc3 = __builtin_amdgcn_mfma_f32_16x16x32_bf16(ap, bv3, oc3, 0, 0, 0);
    }
  }
  // context write (C-layout: row = quad*4+r, col = dc*16+n)
#pragma unroll
  for (int r = 0; r < 4; ++r) {
    int qr = qbase + wave * 16 + quad * 4 + r;
    float* op = out + ((size_t)(bS + qr)) * D_ + n;
    __builtin_nontemporal_store(oc0[r], op + 0);
    __builtin_nontemporal_store(oc1[r], op + 16);
    __builtin_nontemporal_store(oc2[r], op + 32);
    __builtin_nontemporal_store(oc3[r], op + 48);
  }
}

extern "C" void kernel_launch(void* const* d_in, const int* in_sizes, int n_in,
                              void* d_out, int out_size, void* d_ws, size_t ws_size,
                              hipStream_t stream) {
  const float* q = (const float*)d_in[0];
  const float* k = (const float*)d_in[1];
  const float* v = (const float*)d_in[2];
  const int* mask = (const int*)d_in[3];
  float* out = (float*)d_out;

  const size_t elems = (size_t)B_ * S_ * D_;          // 4194304
  const size_t need = 2 * elems * sizeof(unsigned short);  // 16.8 MB
  if (ws_size >= need) {
    unsigned short* K16 = (unsigned short*)d_ws;
    unsigned short* Vt16 = K16 + elems;
    conv_bf16_kernel<<<(int)(elems / 8 / 256), 256, 0, stream>>>(k, K16);
    convVt_kernel<<<dim3(S_ / 64, B_), 256, 0, stream>>>(v, Vt16);
    attn_kernel<true><<<B_ * (S_ / TQ), 256, 0, stream>>>(
        q, K16, Vt16, k, v, mask, out);
  } else {
    attn_kernel<false><<<B_ * (S_ / TQ), 256, 0, stream>>>(
        q, nullptr, nullptr, k, v, mask, out);
  }
}